// Round 17
// baseline (336.305 us; speedup 1.0000x reference)
//
#include <hip/hip_runtime.h>
#include <hip/hip_cooperative_groups.h>
#include <hip/hip_bf16.h>
#include <stdint.h>

namespace cg = cooperative_groups;

#define EMBED  128
#define HIDDEN 512
#define TB     64    // tokens per mlp block
#define HHALF  256   // hidden cols per pass (2 passes)
#define CAP    32    // bucket capacity per vocab row (Poisson lambda=4; P(>32)~1e-19)

typedef __attribute__((ext_vector_type(8))) short short8v;   // 8 bf16 = 4 VGPR
typedef __attribute__((ext_vector_type(8))) ushort ushort8v;
typedef __attribute__((ext_vector_type(4))) float f32x4;

__device__ __forceinline__ ushort f2bf(float f) {
    uint32_t b = __float_as_uint(f);
    uint32_t r = (b + 0x7FFFu + ((b >> 16) & 1u)) >> 16;
    return (ushort)r;
}
__device__ __forceinline__ float bf2f(ushort u) {
    return __uint_as_float(((uint32_t)u) << 16);
}

__device__ __forceinline__ float gelu_fast(float x) {
    // 0.5x(1+tanh(u)) == x - x/(exp(2u)+1),  u = 0.79788456(x + 0.044715x^3)
    float x2 = x * x;
    float u  = x * fmaf(0.035677408136f, x2, 0.7978845608f);
    float t  = __expf(2.0f * u);
    return x - x * __frcp_rn(t + 1.0f);
}

// ===========================================================================
// Shared device body: fused bloom-gather + bf16-MFMA MLP for one 64-token tile
// (exact R12 structure). Used by both the cooperative mega kernel (Phase C)
// and the fallback mlp kernel.
// ===========================================================================
__device__ __forceinline__
void mlp_body(ushort* Xs, ushort* Hs, int t, int blockId,
              const int*    __restrict__ tokens,
              const ushort* __restrict__ tbf,
              const int*    __restrict__ cnt,
              const ushort* __restrict__ csr,
              const ushort* __restrict__ W1t,
              const ushort* __restrict__ W2t,
              const float*  __restrict__ b1,
              const float*  __restrict__ b2,
              float*        __restrict__ out) {
    const int lane = t & 63;
    const int wv   = t >> 6;             // 0..7
    const int base = blockId * TB;
    const int l15  = lane & 15;
    const int lhi  = lane >> 4;          // 0..3

    // ---- X-stage: inline bloom aggregation, 8 threads/token x 16 bf16 cols ----
    {
        int r    = t >> 3;               // 0..63 token row
        int c16  = t & 7;                // 16-col segment (two 8-granules)
        int tok  = tokens[base + r];
        int m    = min(cnt[tok], CAP);
        const ushort* jrow = csr + (size_t)tok * CAP;
        ushort8v jv = *(const ushort8v*)jrow;       // 8 indices, one 16B load

        short8v v[8][2];                 // issue all 16 loads before consume
        #pragma unroll
        for (int e = 0; e < 8; ++e) {
            int j = (e < m) ? (int)jv[e] : 0;
            const ushort* trp = tbf + (size_t)j * EMBED + c16 * 16;
            v[e][0] = *(const short8v*)(trp);
            v[e][1] = *(const short8v*)(trp + 8);
        }
        float acc[16] = {0.f,0.f,0.f,0.f,0.f,0.f,0.f,0.f,
                         0.f,0.f,0.f,0.f,0.f,0.f,0.f,0.f};
        #pragma unroll
        for (int e = 0; e < 8; ++e) {
            if (e < m) {
                #pragma unroll
                for (int q = 0; q < 8; ++q) {
                    acc[q]     += bf2f((ushort)v[e][0][q]);
                    acc[8 + q] += bf2f((ushort)v[e][1][q]);
                }
            }
        }
        for (int e = 8; e < m; ++e) {    // rare tail (P ~2%)
            int j = (int)jrow[e];
            const ushort* trp = tbf + (size_t)j * EMBED + c16 * 16;
            short8v w0 = *(const short8v*)(trp);
            short8v w1v = *(const short8v*)(trp + 8);
            #pragma unroll
            for (int q = 0; q < 8; ++q) {
                acc[q]     += bf2f((ushort)w0[q]);
                acc[8 + q] += bf2f((ushort)w1v[q]);
            }
        }
        ushort u[16];
        #pragma unroll
        for (int q = 0; q < 16; ++q) u[q] = f2bf(0.5f * acc[q]);
        int g0 = c16 * 2;
        #pragma unroll
        for (int h = 0; h < 2; ++h)
            *(short8v*)&Xs[r * EMBED + ((g0 + h) ^ (r & 7)) * 8] = *(short8v*)&u[h * 8];
    }
    __syncthreads();

    // ---- out accumulator persists across both hidden halves ----
    f32x4 acc2[4];
    {
        float bv = b2[wv * 16 + l15];
        #pragma unroll
        for (int m = 0; m < 4; ++m) acc2[m] = (f32x4){bv, bv, bv, bv};
    }

    #pragma unroll
    for (int h = 0; h < 2; ++h) {
        // ---- GEMM1 half: H[64][32 per wave] = X @ W1[:, h*256+wv*32 ...] ----
        f32x4 acc1[4][2];
        #pragma unroll
        for (int n = 0; n < 2; ++n) {
            float bv = b1[h * HHALF + wv * 32 + n * 16 + l15];
            #pragma unroll
            for (int m = 0; m < 4; ++m) acc1[m][n] = (f32x4){bv, bv, bv, bv};
        }
        #pragma unroll
        for (int kk = 0; kk < EMBED / 32; ++kk) {   // 4 k-steps
            short8v a[4];
            #pragma unroll
            for (int m = 0; m < 4; ++m) {
                int r = m * 16 + l15;
                int gg = (kk * 4 + lhi) ^ (r & 7);
                a[m] = *(const short8v*)&Xs[r * EMBED + gg * 8];
            }
            #pragma unroll
            for (int n = 0; n < 2; ++n) {
                int col = h * HHALF + wv * 32 + n * 16 + l15;
                short8v b = *(const short8v*)(W1t + (size_t)col * EMBED + kk * 32 + lhi * 8);
                #pragma unroll
                for (int m = 0; m < 4; ++m)
                    acc1[m][n] = __builtin_amdgcn_mfma_f32_16x16x32_bf16(a[m], b, acc1[m][n], 0, 0, 0);
            }
        }

        // ---- gelu -> bf16 -> swizzled Hs (cols within half: 0..255) ----
        #pragma unroll
        for (int n = 0; n < 2; ++n) {
            int colh = wv * 32 + n * 16 + l15;
            #pragma unroll
            for (int m = 0; m < 4; ++m)
                #pragma unroll
                for (int q = 0; q < 4; ++q) {
                    int row = m * 16 + lhi * 4 + q;
                    float hv = gelu_fast(acc1[m][n][q]);
                    int gg = (colh >> 3) ^ (row & 7);
                    Hs[row * HHALF + gg * 8 + (colh & 7)] = f2bf(hv);
                }
        }
        __syncthreads();

        // ---- GEMM2 half: acc2 += H_half @ W2[h*256 ...] ----
        #pragma unroll
        for (int kk = 0; kk < HHALF / 32; ++kk) {   // 8 k-steps
            short8v a[4];
            #pragma unroll
            for (int m = 0; m < 4; ++m) {
                int r = m * 16 + l15;
                int gg = (kk * 4 + lhi) ^ (r & 7);
                a[m] = *(const short8v*)&Hs[r * HHALF + gg * 8];
            }
            int col = wv * 16 + l15;
            short8v b = *(const short8v*)(W2t + (size_t)col * HIDDEN + h * HHALF + kk * 32 + lhi * 8);
            #pragma unroll
            for (int m = 0; m < 4; ++m)
                acc2[m] = __builtin_amdgcn_mfma_f32_16x16x32_bf16(a[m], b, acc2[m], 0, 0, 0);
        }
        __syncthreads();    // before next half overwrites Hs
    }

    // ---- store ----
    #pragma unroll
    for (int m = 0; m < 4; ++m)
        #pragma unroll
        for (int q = 0; q < 4; ++q) {
            int row = m * 16 + lhi * 4 + q;
            out[(size_t)(base + row) * EMBED + wv * 16 + l15] = acc2[m][q];
        }
}

// ===========================================================================
// Cooperative single-kernel path
// ===========================================================================
__global__ __launch_bounds__(512, 4)
void mega_kernel(const int*   __restrict__ tokens,
                 const float* __restrict__ table,
                 const int*   __restrict__ bi,
                 const int*   __restrict__ bj, int nk,
                 const float* __restrict__ w1,
                 const float* __restrict__ b1,
                 const float* __restrict__ w2,
                 const float* __restrict__ b2,
                 ushort* __restrict__ W1t, ushort* __restrict__ W2t,
                 ushort* __restrict__ tbf, ushort* __restrict__ csr,
                 int*    __restrict__ cnt,
                 float*  __restrict__ out,
                 int vocab, int ntok) {
    __shared__ ushort Xs[TB * EMBED];    // 16 KB
    __shared__ ushort Hs[TB * HHALF];    // 32 KB

    cg::grid_group grid = cg::this_grid();
    const int t  = threadIdx.x;
    const int g  = blockIdx.x * 512 + t;
    const int GT = gridDim.x * 512;

    // Phase A: weight transpose + zero cnt + table convert (all independent)
    if (g < EMBED * HIDDEN) {
        int k = g & 127, n = g >> 7;
        W1t[g] = f2bf(w1[k * HIDDEN + n]);
    } else if (g < 2 * EMBED * HIDDEN) {
        int h = g - EMBED * HIDDEN;
        int k = h & 511, n = h >> 9;
        W2t[h] = f2bf(w2[k * EMBED + n]);
    } else if (g < 2 * EMBED * HIDDEN + vocab) {
        cnt[g - 2 * EMBED * HIDDEN] = 0;
    }
    int n8 = vocab * (EMBED / 8);
    for (int gr = g; gr < n8; gr += GT) {
        const float* src = table + (size_t)gr * 8;
        float4 v0 = *(const float4*)(src);
        float4 v1 = *(const float4*)(src + 4);
        ushort u[8] = {f2bf(v0.x), f2bf(v0.y), f2bf(v0.z), f2bf(v0.w),
                       f2bf(v1.x), f2bf(v1.y), f2bf(v1.z), f2bf(v1.w)};
        *(short8v*)&tbf[(size_t)gr * 8] = *(short8v*)u;
    }
    __threadfence();
    grid.sync();

    // Phase B: bucket
    for (int k = g; k < nk; k += GT) {
        int i = bi[k];
        int slot = atomicAdd(&cnt[i], 1);
        if (slot < CAP) csr[(size_t)i * CAP + slot] = (ushort)bj[k];
    }
    __threadfence();
    grid.sync();

    // Phase C: fused gather + MFMA MLP
    mlp_body(Xs, Hs, t, blockIdx.x, tokens, tbf, cnt, csr, W1t, W2t, b1, b2, out);
}

// ===========================================================================
// Fallback path (exact R12): zero -> prep -> mlp
// ===========================================================================
__global__ void zero_kernel(int* __restrict__ p, int n) {
    int i = blockIdx.x * blockDim.x + threadIdx.x;
    if (i < n) p[i] = 0;
}

__global__ __launch_bounds__(256)
void prep_kernel(const float* __restrict__ w1, const float* __restrict__ w2,
                 ushort* __restrict__ W1t, ushort* __restrict__ W2t,
                 const float* __restrict__ table, ushort* __restrict__ tbf, int n8, int cb,
                 const int* __restrict__ bi, const int* __restrict__ bj, int nk,
                 int* __restrict__ cnt, ushort* __restrict__ csr) {
    __shared__ float T[32][33];
    int b = blockIdx.x;
    int t = threadIdx.x;
    if (b < 128) {
        const float* in; ushort* outp; int inCols, outCols, tr, tc;
        if (b < 64) {            // W1: [128][512] -> W1t [512][128]
            in = w1; outp = W1t; inCols = 512; outCols = 128;
            tr = b >> 4; tc = b & 15;
        } else {                 // W2: [512][128] -> W2t [128][512]
            int b2 = b - 64;
            in = w2; outp = W2t; inCols = 128; outCols = 512;
            tr = b2 >> 2; tc = b2 & 3;
        }
        int r  = t >> 3;
        int c4 = (t & 7) * 4;
        float4 v = *(const float4*)&in[(size_t)(tr * 32 + r) * inCols + tc * 32 + c4];
        T[c4 + 0][r] = v.x; T[c4 + 1][r] = v.y; T[c4 + 2][r] = v.z; T[c4 + 3][r] = v.w;
        __syncthreads();
        ushort o[4];
        #pragma unroll
        for (int i = 0; i < 4; ++i) o[i] = f2bf(T[r][c4 + i]);
        *(ushort4*)&outp[(size_t)(tc * 32 + r) * outCols + tr * 32 + c4] = *(ushort4*)o;
    } else if (b < 128 + cb) {
        int gid = (b - 128) * 256 + t;
        if (gid < n8) {
            const float* src = table + (size_t)gid * 8;
            float4 v0 = *(const float4*)(src);
            float4 v1 = *(const float4*)(src + 4);
            ushort u[8] = {f2bf(v0.x), f2bf(v0.y), f2bf(v0.z), f2bf(v0.w),
                           f2bf(v1.x), f2bf(v1.y), f2bf(v1.z), f2bf(v1.w)};
            *(short8v*)&tbf[(size_t)gid * 8] = *(short8v*)u;
        }
    } else {
        int k = (b - 128 - cb) * 256 + t;
        if (k < nk) {
            int i = bi[k];
            int slot = atomicAdd(&cnt[i], 1);
            if (slot < CAP) csr[(size_t)i * CAP + slot] = (ushort)bj[k];
        }
    }
}

__global__ __launch_bounds__(512)
void mlp_mfma_kernel(const int*    __restrict__ tokens,
                     const ushort* __restrict__ tbf,
                     const int*    __restrict__ cnt,
                     const ushort* __restrict__ csr,
                     const ushort* __restrict__ W1t,
                     const ushort* __restrict__ W2t,
                     const float*  __restrict__ b1,
                     const float*  __restrict__ b2,
                     float*        __restrict__ out) {
    __shared__ ushort Xs[TB * EMBED];
    __shared__ ushort Hs[TB * HHALF];
    mlp_body(Xs, Hs, threadIdx.x, blockIdx.x, tokens, tbf, cnt, csr, W1t, W2t, b1, b2, out);
}

// ---------------------------------------------------------------------------
extern "C" void kernel_launch(void* const* d_in, const int* in_sizes, int n_in,
                              void* d_out, int out_size, void* d_ws, size_t ws_size,
                              hipStream_t stream) {
    const int*   tokens = (const int*)  d_in[0];
    const float* table  = (const float*)d_in[1];
    const int*   bi     = (const int*)  d_in[2];
    const int*   bj     = (const int*)  d_in[3];
    const float* w1     = (const float*)d_in[4];
    const float* b1     = (const float*)d_in[5];
    const float* w2     = (const float*)d_in[6];
    const float* b2     = (const float*)d_in[7];
    float* out = (float*)d_out;

    const int vocab = in_sizes[1] / EMBED;   // 50257
    int nk    = in_sizes[2];                 // 4 * vocab
    int ntok  = in_sizes[0];                 // 32768

    // ---- workspace layout (~17 MB) ----
    char* ws = (char*)d_ws;
    size_t off = 0;
    auto alloc = [&](size_t b) { size_t o = off; off += (b + 255) & ~(size_t)255; return o; };
    ushort* W1t = (ushort*)(ws + alloc((size_t)EMBED * HIDDEN * 2));
    ushort* W2t = (ushort*)(ws + alloc((size_t)EMBED * HIDDEN * 2));
    ushort* tbf = (ushort*)(ws + alloc((size_t)vocab * EMBED * 2));
    ushort* csr = (ushort*)(ws + alloc((size_t)vocab * CAP * 2));
    int*    cnt = (int*)   (ws + alloc((size_t)vocab * 4));

    int vocab_i = vocab;
    void* args[] = {
        (void*)&tokens, (void*)&table, (void*)&bi, (void*)&bj, (void*)&nk,
        (void*)&w1, (void*)&b1, (void*)&w2, (void*)&b2,
        (void*)&W1t, (void*)&W2t, (void*)&tbf, (void*)&csr, (void*)&cnt,
        (void*)&out, (void*)&vocab_i, (void*)&ntok
    };
    hipError_t err = hipLaunchCooperativeKernel((void*)mega_kernel,
                                                dim3(ntok / TB), dim3(512),
                                                args, 0, stream);
    if (err != hipSuccess) {
        // ---- fallback: proven R12 three-kernel path ----
        zero_kernel<<<(vocab + 255) / 256, 256, 0, stream>>>(cnt, vocab);
        int n8 = vocab * EMBED / 8;
        int cb = (n8 + 255) / 256;
        int bb = (nk + 255) / 256;
        prep_kernel<<<128 + cb + bb, 256, 0, stream>>>(w1, w2, W1t, W2t,
                                                       table, tbf, n8, cb,
                                                       bi, bj, nk, cnt, csr);
        mlp_mfma_kernel<<<ntok / TB, 512, 0, stream>>>(tokens, tbf, cnt, csr,
                                                       W1t, W2t, b1, b2, out);
    }
}